// Round 6
// baseline (345.779 us; speedup 1.0000x reference)
//
#include <hip/hip_runtime.h>
#include <hip/hip_bf16.h>

typedef __hip_bfloat16 bf16;
typedef _Float16 fp16;
typedef short bf16x8 __attribute__((ext_vector_type(8)));
typedef float f32x4 __attribute__((ext_vector_type(4)));
typedef _Float16 half8 __attribute__((ext_vector_type(8)));
typedef _Float16 half2v __attribute__((ext_vector_type(2)));

#define BB 2
#define LL 512
#define HH 2048
#define DI 4096
#define NST 16
#define KK 4
#define RR 128
#define BLM (BB*LL)   // 1024 rows
#define CN 16         // scan chunks
#define LC (LL/CN)    // 32 steps per chunk
#define ZXP 16        // xproj split-K
#define ZOUT 4        // out split-K
#define CONV_N (BLM*DI)
#define CONV8_N (CONV_N/8)
#define CVT4_N (HH*DI/4)

enum { MODE_PROJ = 0, MODE_XPROJ = 1, MODE_DT = 2, MODE_OUT = 3 };

__device__ __forceinline__ float sigmoidf_(float x) { return 1.f / (1.f + __expf(-x)); }
__device__ __forceinline__ float softplusf_(float x) {
    return fmaxf(x, 0.f) + log1pf(__expf(-fabsf(x)));
}
__device__ __forceinline__ unsigned int bfpack(float a, float b) {
    __hip_bfloat162 h = __float22bfloat162_rn(make_float2(a, b));
    union { __hip_bfloat162 h; unsigned int u; } cv; cv.h = h;
    return cv.u;
}
__device__ __forceinline__ float b2f(short s) {
    union { unsigned u; float f; } c; c.u = ((unsigned)(unsigned short)s) << 16; return c.f;
}

typedef const __attribute__((address_space(1))) unsigned int* gas_t;
typedef __attribute__((address_space(3))) unsigned int* las_t;
__device__ __forceinline__ void gld16(const void* g, void* l) {
    __builtin_amdgcn_global_load_lds((gas_t)g, (las_t)l, 16, 0, 0);
}

__device__ __forceinline__ void cvt_seg(const float* s, bf16* d, int i) {
    float4 v = ((const float4*)s)[i];
    uint2 o; o.x = bfpack(v.x, v.y); o.y = bfpack(v.z, v.w);
    ((uint2*)d)[i] = o;
}

// fused fp32->bf16 for 4 tensors, grid-stride over concatenated float4 ranges
__global__ __launch_bounds__(256) void cvt_all(
    const float* __restrict__ s0, bf16* __restrict__ d0, int n0,
    const float* __restrict__ s1, bf16* __restrict__ d1, int n1,
    const float* __restrict__ s2, bf16* __restrict__ d2, int n2,
    const float* __restrict__ s3, bf16* __restrict__ d3, int n3)
{
    int i = blockIdx.x * 256 + threadIdx.x;
    int stride = gridDim.x * 256;
    int t1 = n0 + n1, t2 = t1 + n2, t3 = t2 + n3;
    for (; i < t3; i += stride) {
        if      (i < n0) cvt_seg(s0, d0, i);
        else if (i < t1) cvt_seg(s1, d1, i - n0);
        else if (i < t2) cvt_seg(s2, d2, i - t1);
        else             cvt_seg(s3, d3, i - t2);
    }
}

// C = A(M,K;lda)bf16 @ B(N,K;ldb)^T bf16, fp32 accum, global_load_lds staging.
// BK=64: 16 MFMA per barrier-pair per wave; LDS rows 128B (8x16B chunks) with
// XOR swizzle chunk^=(row&7): linear gld16 dest, swizzled GLOBAL src, mirrored read.
template<int BM, int BN, int MODE>
__global__ __launch_bounds__(256) void gemm_bf16(
    const bf16* __restrict__ A, const bf16* __restrict__ Bw,
    int N, int K, int lda, int ldb,
    const float* __restrict__ bias,
    bf16* __restrict__ outh, bf16* __restrict__ outh2,
    fp16* __restrict__ s0, fp16* __restrict__ s1,
    fp16* __restrict__ s2, fp16* __restrict__ s3)
{
    __shared__ short sA[BM * 64];
    __shared__ short sB[BN * 64];
    const int tid = threadIdx.x;
    const int col0 = blockIdx.x * BN;
    const int row0 = blockIdx.y * BM;
    const int wave = tid >> 6;
    const int lane = tid & 63;
    constexpr int NJ = (BM == 64 || BN == 64) ? 2 : 4;
    const int wr = (BM == 128) ? ((wave >> 1) * 64) : 0;
    const int wc = (BM == 64) ? (wave * 32) : ((wave & 1) * (BN / 2));
    const int lr = lane & 15;
    const int q  = lane >> 4;       // logical 16B chunk within 32-col substep
    const int sw = lane & 7;        // row&7 of every row this lane reads

    const int kpb = K / gridDim.z;
    const int kbeg = blockIdx.z * kpb;
    const int kend = kbeg + kpb;

    const int r0 = tid >> 3;                               // 0..31 (LDS row per pass)
    const int kc  = (tid & 7) << 3;                        // linear LDS dest chunk (shorts)
    const int kcs = (((tid & 7) ^ ((tid >> 3) & 7)) << 3); // swizzled global src chunk

    f32x4 acc[4][NJ] = {};

    for (int k0 = kbeg; k0 < kend; k0 += 64) {
        #pragma unroll
        for (int p = 0; p < BM / 32; p++) {
            int r = r0 + p * 32;
            gld16(A + (size_t)(row0 + r) * lda + k0 + kcs, &sA[r * 64 + kc]);
        }
        #pragma unroll
        for (int p = 0; p < BN / 32; p++) {
            int rr = r0 + p * 32;
            int nb = col0 + rr; if (nb > N - 1) nb = N - 1;   // clamp (epilogue guards)
            gld16(Bw + (size_t)nb * ldb + k0 + kcs, &sB[rr * 64 + kc]);
        }
        __syncthreads();
        bf16x8 af[2][4], bfr[2][NJ];
        #pragma unroll
        for (int kk = 0; kk < 2; kk++) {
            const int cs = ((kk * 4 + q) ^ sw) << 3;
            #pragma unroll
            for (int i = 0; i < 4; i++)
                af[kk][i] = *(const bf16x8*)(&sA[(wr + i * 16 + lr) * 64 + cs]);
            #pragma unroll
            for (int j = 0; j < NJ; j++)
                bfr[kk][j] = *(const bf16x8*)(&sB[(wc + j * 16 + lr) * 64 + cs]);
        }
        #pragma unroll
        for (int kk = 0; kk < 2; kk++)
            #pragma unroll
            for (int i = 0; i < 4; i++)
                #pragma unroll
                for (int j = 0; j < NJ; j++)
                    acc[i][j] = __builtin_amdgcn_mfma_f32_16x16x32_bf16(af[kk][i], bfr[kk][j], acc[i][j], 0, 0, 0);
        __syncthreads();
    }

    fp16* oslice = s0;
    if (MODE == MODE_OUT) {
        int z = blockIdx.z;
        oslice = (z == 0) ? s0 : (z == 1) ? s1 : (z == 2) ? s2 : s3;
    }
    const int drow = (lane >> 4) << 2;
    const int dcol = lane & 15;
    #pragma unroll
    for (int i = 0; i < 4; i++) {
        #pragma unroll
        for (int j = 0; j < NJ; j++) {
            int n = col0 + wc + j * 16 + dcol;
            if (n >= N) continue;
            float bv = bias ? bias[n] : 0.f;
            #pragma unroll
            for (int r = 0; r < 4; r++) {
                int m = row0 + wr + i * 16 + drow + r;
                float v = acc[i][j][r];
                if (MODE == MODE_PROJ) {
                    v += bv;
                    if (n < DI) outh2[(size_t)m * DI + n] = (bf16)v;         // h bf16
                    else        outh[(size_t)m * DI + (n - DI)] = (bf16)v;   // gate bf16
                } else if (MODE == MODE_XPROJ) {
                    s0[(size_t)blockIdx.z * (BLM * 160) + (size_t)m * 160 + n] = (fp16)v;
                } else if (MODE == MODE_DT) {
                    s0[(size_t)m * DI + n] = (fp16)softplusf_(v + bv);       // dt fp16
                } else { // MODE_OUT: fp16 per-slice partial
                    oslice[(size_t)m * HH + n] = (fp16)v;
                }
            }
        }
    }
}

// fused: depthwise causal conv K=4 + silu, 8 d's/thread (vectorized bf16x8 loads),
// AND out_w fp32->bf16 conversion appended.
__global__ __launch_bounds__(256) void conv_cvtow(
    const bf16* __restrict__ h, const float* __restrict__ conv_w,
    const float* __restrict__ conv_b, bf16* __restrict__ hs_b,
    const float* __restrict__ ow, bf16* __restrict__ ow_b)
{
    int i = blockIdx.x * 256 + threadIdx.x;
    int stride = gridDim.x * 256;
    for (; i < CONV8_N + CVT4_N; i += stride) {
        if (i < CONV8_N) {
            int idx = i << 3;                  // element index, multiple of 8
            int d0 = idx & (DI - 1);
            int l = (idx >> 12) & (LL - 1);
            float4 cb0 = *(const float4*)&conv_b[d0];
            float4 cb1 = *(const float4*)&conv_b[d0 + 4];
            float acc[8] = {cb0.x, cb0.y, cb0.z, cb0.w, cb1.x, cb1.y, cb1.z, cb1.w};
            float4 w[8];
            #pragma unroll
            for (int j = 0; j < 8; j++) w[j] = *(const float4*)&conv_w[(d0 + j) * KK];
            #pragma unroll
            for (int k = 0; k < KK; k++) {
                int ls = l - (KK - 1) + k;
                if (ls >= 0) {
                    bf16x8 hv = *(const bf16x8*)&h[(size_t)idx + (size_t)(ls - l) * DI];
                    #pragma unroll
                    for (int j = 0; j < 8; j++)
                        acc[j] += b2f(hv[j]) * ((const float*)&w[j])[k];
                }
            }
            uint4 o;
            float s0 = acc[0] * sigmoidf_(acc[0]), s1 = acc[1] * sigmoidf_(acc[1]);
            float s2 = acc[2] * sigmoidf_(acc[2]), s3 = acc[3] * sigmoidf_(acc[3]);
            float s4 = acc[4] * sigmoidf_(acc[4]), s5 = acc[5] * sigmoidf_(acc[5]);
            float s6 = acc[6] * sigmoidf_(acc[6]), s7 = acc[7] * sigmoidf_(acc[7]);
            o.x = bfpack(s0, s1); o.y = bfpack(s2, s3);
            o.z = bfpack(s4, s5); o.w = bfpack(s6, s7);
            *(uint4*)&hs_b[idx] = o;
        } else {
            cvt_seg(ow, ow_b, i - CONV8_N);
        }
    }
}

// sum 16 fp16 xproj slices -> sp fp32; cols<128 also -> ts bf16 (2 cols/thread,
// 320 blocks for occupancy; coalesced 4B loads)
__global__ __launch_bounds__(256) void reduce_sp(
    const fp16* __restrict__ spS, float* __restrict__ sp_f, bf16* __restrict__ ts_b)
{
    int i = blockIdx.x * 256 + threadIdx.x;     // 81920 items (exact)
    int row = i / 80, c2 = (i % 80) * 2;
    float r0 = 0.f, r1 = 0.f;
    #pragma unroll
    for (int z = 0; z < ZXP; z++) {
        half2v v = *(const half2v*)&spS[(size_t)z * (BLM * 160) + (size_t)row * 160 + c2];
        r0 += (float)v[0]; r1 += (float)v[1];
    }
    *(float2*)&sp_f[(size_t)row * 160 + c2] = make_float2(r0, r1);
    if (c2 < RR) *(unsigned*)&ts_b[(size_t)row * RR + c2] = bfpack(r0, r1);
}

// sum 4 fp16 out slices + bias -> d_out fp32 (8 elems/thread)
__global__ __launch_bounds__(256) void reduce_out(
    const fp16* __restrict__ s0, const fp16* __restrict__ s1,
    const fp16* __restrict__ s2, const fp16* __restrict__ s3,
    const float* __restrict__ bias, float* __restrict__ out)
{
    int i = blockIdx.x * 256 + threadIdx.x;     // 262144 groups of 8
    int c8 = (i & 255) << 3;
    half8 a = ((const half8*)s0)[i];
    half8 b = ((const half8*)s1)[i];
    half8 c = ((const half8*)s2)[i];
    half8 d = ((const half8*)s3)[i];
    float r[8];
    #pragma unroll
    for (int e = 0; e < 8; e++)
        r[e] = (float)a[e] + (float)b[e] + (float)c[e] + (float)d[e] + bias[c8 + e];
    ((float4*)out)[2 * i]     = make_float4(r[0], r[1], r[2], r[3]);
    ((float4*)out)[2 * i + 1] = make_float4(r[4], r[5], r[6], r[7]);
}

// Chunked scan pass 1, 4-way n-split by WAVE: wave ng owns states 4ng..4ng+3,
// lanes = 64 consecutive d -> fully coalesced dt/hs loads and P/S stores.
__global__ __launch_bounds__(256) void scan_part1(
    const fp16* __restrict__ dtr, const float* __restrict__ sp,
    const bf16* __restrict__ hs_b, const float* __restrict__ A_log,
    float* __restrict__ P_ws, float* __restrict__ S_ws)
{
    int bid = blockIdx.x;
    int c  = bid & (CN - 1);
    int db = (bid >> 4) & 63;          // DI/64
    int b  = bid >> 10;
    int ng = threadIdx.x >> 6;         // wave id -> state group
    int d  = db * 64 + (threadIdx.x & 63);
    int n0 = ng * 4;

    float A[4], P[4], S[4];
    #pragma unroll
    for (int k = 0; k < 4; k++) {
        A[k] = -__expf(A_log[d * NST + n0 + k]);
        P[k] = 1.f; S[k] = 0.f;
    }
    const float* spb = sp + (size_t)b * LL * 160;
    size_t base = (size_t)b * LL * DI + d;
    for (int l = c * LC; l < (c + 1) * LC; l++) {
        size_t off = base + (size_t)l * DI;
        float dtv = (float)dtr[off];
        float hsv = (float)hs_b[off];
        float dh = dtv * hsv;
        #pragma unroll
        for (int k = 0; k < 4; k++) {
            float a  = __expf(dtv * A[k]);
            float Bn = spb[l * 160 + RR + n0 + k];
            S[k] = a * S[k] + dh * Bn;
            P[k] *= a;
        }
    }
    size_t ob = (size_t)(b * CN + c) * NST * DI + (size_t)n0 * DI + d;
    #pragma unroll
    for (int k = 0; k < 4; k++) {
        P_ws[ob + (size_t)k * DI] = P[k];
        S_ws[ob + (size_t)k * DI] = S[k];
    }
}

// Hierarchical prefix: scan the CN chunk summaries per (b,n,d); overwrite S_ws
// with each chunk's INITIAL state (I[c] = state before chunk c). ~24MB traffic.
__global__ __launch_bounds__(256) void scan_mid(
    const float* __restrict__ P_ws, float* __restrict__ S_ws)
{
    int bid = blockIdx.x;
    int n  = bid & (NST - 1);
    int db = (bid >> 4) & (DI / 256 - 1);
    int b  = bid >> 8;
    int d  = db * 256 + threadIdx.x;
    size_t base = (size_t)n * DI + d;
    float s = 0.f;
    for (int c = 0; c < CN; c++) {
        size_t idx = (size_t)(b * CN + c) * NST * DI + base;
        float p  = P_ws[idx];
        float sv = S_ws[idx];
        S_ws[idx] = s;            // init state for chunk c
        s = p * s + sv;
    }
}

// Pass 2, 4-way n-split within wave (shfl y-reduce): load chunk-init state from
// I (=S_ws), local scan, y closed with two width-4 shfl_xor adds.
__global__ __launch_bounds__(256) void scan_part2(
    const fp16* __restrict__ dtr, const float* __restrict__ sp,
    const bf16* __restrict__ hs_b, const bf16* __restrict__ g_b,
    const float* __restrict__ A_log, const float* __restrict__ Dv,
    const float* __restrict__ I_ws, bf16* __restrict__ y_b)
{
    int bid = blockIdx.x;
    int c  = bid & (CN - 1);
    int db = (bid >> 4) & 63;          // DI/64
    int b  = bid >> 10;
    int ng = threadIdx.x & 3;
    int d  = db * 64 + (threadIdx.x >> 2);
    int n0 = ng * 4;

    float A[4], s[4];
    #pragma unroll
    for (int k = 0; k < 4; k++)
        A[k] = -__expf(A_log[d * NST + n0 + k]);
    size_t ib = (size_t)(b * CN + c) * NST * DI + (size_t)n0 * DI + d;
    #pragma unroll
    for (int k = 0; k < 4; k++) s[k] = I_ws[ib + (size_t)k * DI];
    float Dd = Dv[d];

    const float* spb = sp + (size_t)b * LL * 160;
    size_t base = (size_t)b * LL * DI + d;
    for (int l = c * LC; l < (c + 1) * LC; l++) {
        size_t off = base + (size_t)l * DI;
        float dtv = (float)dtr[off];
        float hsv = (float)hs_b[off];
        float dh = dtv * hsv;
        float y = 0.f;
        #pragma unroll
        for (int k = 0; k < 4; k++) {
            float a  = __expf(dtv * A[k]);
            float Bn = spb[l * 160 + RR + n0 + k];
            float Cn = spb[l * 160 + RR + NST + n0 + k];
            s[k] = a * s[k] + dh * Bn;
            y += s[k] * Cn;
        }
        y += __shfl_xor(y, 1);
        y += __shfl_xor(y, 2);
        if (ng == 0) {
            float gv = (float)g_b[off];
            y_b[off] = (bf16)((y + hsv * Dd) * (gv * sigmoidf_(gv)));
        }
    }
}

extern "C" void kernel_launch(void* const* d_in, const int* in_sizes, int n_in,
                              void* d_out, int out_size, void* d_ws, size_t ws_size,
                              hipStream_t stream)
{
    const float* x       = (const float*)d_in[0];
    const float* in_w    = (const float*)d_in[1];
    const float* in_b    = (const float*)d_in[2];
    const float* conv_w  = (const float*)d_in[3];
    const float* conv_b  = (const float*)d_in[4];
    const float* xproj_w = (const float*)d_in[5];
    const float* dt_w    = (const float*)d_in[6];
    const float* dt_b    = (const float*)d_in[7];
    const float* A_log   = (const float*)d_in[8];
    const float* Dv      = (const float*)d_in[9];
    const float* out_w   = (const float*)d_in[10];
    const float* out_b   = (const float*)d_in[11];
    float* out = (float*)d_out;

    // Overlay layout, 67.2 MB peak.
    // [0,8):   h_b (D1-D2) -> spS fp16 5.25 (D3-D4) -> P (D6, dead after mid) -> oS0[0,4)+oS1[4,8) (D8-D9)
    // [8,16):  x_b [8,12) (D0-D1) -> S/I (D6-D7) -> oS2[8,12)+oS3[12,16) (D8-D9)
    // [16,32): in_w_b part (D0-D1) -> ow_b bf16 (D2-D8)
    // [32,40): in_w_b part -> y_b (D7-D8)
    // [40,48): in_w_b part -> dt_h fp16 (D5-D7)
    // [48,56): hs_b (D2-D7)
    // [56,64): g_b (D1-D7)
    // [64,67.2): sp_f, ts_b, xw_b, dtw_b
    char* ws = (char*)d_ws;
    const size_t MB = 1u << 20;
    bf16*  h_b    = (bf16*)(ws);
    fp16*  spS    = (fp16*)(ws);
    float* P_ws   = (float*)(ws);
    fp16*  oS0    = (fp16*)(ws);
    fp16*  oS1    = (fp16*)(ws + 4 * MB);
    bf16*  x_b    = (bf16*)(ws + 8 * MB);
    float* S_ws   = (float*)(ws + 8 * MB);
    fp16*  oS2    = (fp16*)(ws + 8 * MB);
    fp16*  oS3    = (fp16*)(ws + 12 * MB);
    bf16*  in_w_b = (bf16*)(ws + 16 * MB);
    bf16*  ow_b   = (bf16*)(ws + 16 * MB);
    bf16*  y_b    = (bf16*)(ws + 32 * MB);
    fp16*  dt_h   = (fp16*)(ws + 40 * MB);
    bf16*  hs_b   = (bf16*)(ws + 48 * MB);
    bf16*  g_b    = (bf16*)(ws + 56 * MB);
    char* p = ws + 64 * MB;
    float* sp_f = (float*)p; p += (size_t)BLM * 160 * 4;        // 0.625 MB
    bf16*  ts_b = (bf16*)p;  p += (size_t)BLM * RR * 2;         // 0.25 MB
    bf16*  xw_b = (bf16*)p;  p += (size_t)(RR + 2 * NST) * DI * 2;  // 1.25 MB
    bf16*  dtw_b= (bf16*)p;  p += (size_t)DI * RR * 2;          // 1 MB

    // D0: fused convert x + in_w + xproj_w + dt_w to bf16
    cvt_all<<<2048, 256, 0, stream>>>(
        x, x_b, BLM * HH / 4,
        in_w, in_w_b, 2 * DI * HH / 4,
        xproj_w, xw_b, (RR + 2 * NST) * DI / 4,
        dt_w, dtw_b, DI * RR / 4);
    // D1: proj = x @ in_w^T + in_b -> h bf16, gate bf16
    gemm_bf16<128, 64, MODE_PROJ><<<dim3((2 * DI) / 64, BLM / 128, 1), 256, 0, stream>>>(
        x_b, in_w_b, 2 * DI, HH, HH, HH, in_b, g_b, h_b,
        nullptr, nullptr, nullptr, nullptr);
    // D2: conv+silu -> hs bf16 (8 d/thread); fused out_w fp32->bf16
    conv_cvtow<<<2048, 256, 0, stream>>>(h_b, conv_w, conv_b, hs_b, out_w, ow_b);
    // D3: sp partials fp16 (BM=64, split-K=16)
    gemm_bf16<64, 128, MODE_XPROJ><<<dim3(2, BLM / 64, ZXP), 256, 0, stream>>>(
        hs_b, xw_b, RR + 2 * NST, DI, DI, DI, nullptr, nullptr, nullptr,
        spS, nullptr, nullptr, nullptr);
    // D4: reduce fp16 slices -> sp fp32 + ts bf16 (320 blocks)
    reduce_sp<<<320, 256, 0, stream>>>(spS, sp_f, ts_b);
    // D5: dt = softplus(ts @ dt_w^T + dt_b) -> fp16
    gemm_bf16<64, 128, MODE_DT><<<dim3(DI / 128, BLM / 64, 1), 256, 0, stream>>>(
        ts_b, dtw_b, DI, RR, RR, RR, dt_b, nullptr, nullptr,
        dt_h, nullptr, nullptr, nullptr);
    // D6: chunk summaries (wave-n-split, coalesced)
    scan_part1<<<BB * (DI / 64) * CN, 256, 0, stream>>>(
        dt_h, sp_f, hs_b, A_log, P_ws, S_ws);
    // D6.5: hierarchical prefix -> chunk-initial states in-place over S_ws
    scan_mid<<<BB * NST * (DI / 256), 256, 0, stream>>>(P_ws, S_ws);
    // D7: local rescan + y emit (no prefix loop)
    scan_part2<<<BB * (DI / 64) * CN, 256, 0, stream>>>(
        dt_h, sp_f, hs_b, g_b, A_log, Dv, S_ws, y_b);
    // D8: out partials (BN=64, split-K=4; fp16 per-slice stores)
    gemm_bf16<128, 64, MODE_OUT><<<dim3(HH / 64, BLM / 128, ZOUT), 256, 0, stream>>>(
        y_b, ow_b, HH, DI, DI, DI, nullptr, nullptr, nullptr,
        oS0, oS1, oS2, oS3);
    // D9: reduce fp16 + bias -> d_out
    reduce_out<<<1024, 256, 0, stream>>>(oS0, oS1, oS2, oS3, out_b, out);
}

// Round 7
// 343.426 us; speedup vs baseline: 1.0069x; 1.0069x over previous
//
#include <hip/hip_runtime.h>
#include <hip/hip_bf16.h>

typedef __hip_bfloat16 bf16;
typedef _Float16 fp16;
typedef short bf16x8 __attribute__((ext_vector_type(8)));
typedef float f32x4 __attribute__((ext_vector_type(4)));
typedef _Float16 half8 __attribute__((ext_vector_type(8)));
typedef _Float16 half2v __attribute__((ext_vector_type(2)));

#define BB 2
#define LL 512
#define HH 2048
#define DI 4096
#define NST 16
#define KK 4
#define RR 128
#define BLM (BB*LL)   // 1024 rows
#define CN 16         // scan chunks
#define LC (LL/CN)    // 32 steps per chunk
#define ZXP 16        // xproj split-K
#define ZOUT 4        // out split-K
#define CONV_N (BLM*DI)
#define CONV8_N (CONV_N/8)
#define CVT4_N (HH*DI/4)

enum { MODE_PROJ = 0, MODE_XPROJ = 1, MODE_DT = 2, MODE_OUT = 3 };

__device__ __forceinline__ float sigmoidf_(float x) { return 1.f / (1.f + __expf(-x)); }
__device__ __forceinline__ float softplusf_(float x) {
    return fmaxf(x, 0.f) + log1pf(__expf(-fabsf(x)));
}
__device__ __forceinline__ unsigned int bfpack(float a, float b) {
    __hip_bfloat162 h = __float22bfloat162_rn(make_float2(a, b));
    union { __hip_bfloat162 h; unsigned int u; } cv; cv.h = h;
    return cv.u;
}
__device__ __forceinline__ float b2f(short s) {
    union { unsigned u; float f; } c; c.u = ((unsigned)(unsigned short)s) << 16; return c.f;
}

typedef const __attribute__((address_space(1))) unsigned int* gas_t;
typedef __attribute__((address_space(3))) unsigned int* las_t;
__device__ __forceinline__ void gld16(const void* g, void* l) {
    __builtin_amdgcn_global_load_lds((gas_t)g, (las_t)l, 16, 0, 0);
}

__device__ __forceinline__ void cvt_seg(const float* s, bf16* d, int i) {
    float4 v = ((const float4*)s)[i];
    uint2 o; o.x = bfpack(v.x, v.y); o.y = bfpack(v.z, v.w);
    ((uint2*)d)[i] = o;
}

// fused fp32->bf16 for 4 tensors, grid-stride over concatenated float4 ranges
__global__ __launch_bounds__(256) void cvt_all(
    const float* __restrict__ s0, bf16* __restrict__ d0, int n0,
    const float* __restrict__ s1, bf16* __restrict__ d1, int n1,
    const float* __restrict__ s2, bf16* __restrict__ d2, int n2,
    const float* __restrict__ s3, bf16* __restrict__ d3, int n3)
{
    int i = blockIdx.x * 256 + threadIdx.x;
    int stride = gridDim.x * 256;
    int t1 = n0 + n1, t2 = t1 + n2, t3 = t2 + n3;
    for (; i < t3; i += stride) {
        if      (i < n0) cvt_seg(s0, d0, i);
        else if (i < t1) cvt_seg(s1, d1, i - n0);
        else if (i < t2) cvt_seg(s2, d2, i - t1);
        else             cvt_seg(s3, d3, i - t2);
    }
}

// C = A(M,K;lda)bf16 @ B(N,K;ldb)^T bf16, fp32 accum, global_load_lds staging.
// BK=64, 2-barrier loop. 128x128 tile (wave-tile 64x64) for proj/out: LDS
// bytes/MFMA = 0.75KB vs 1.125KB at 128x64 -> LDS-BW cap rises 44%->66%.
// LDS rows 128B (8x16B chunks), XOR swizzle chunk^=(row&7): linear gld16 dest,
// swizzled GLOBAL src chunk, mirrored read (row&7 == lane&7 since all row
// offsets are multiples of 16).
template<int BM, int BN, int MODE>
__global__ __launch_bounds__(256) void gemm_bf16(
    const bf16* __restrict__ A, const bf16* __restrict__ Bw,
    int N, int K, int lda, int ldb,
    const float* __restrict__ bias,
    bf16* __restrict__ outh, bf16* __restrict__ outh2,
    fp16* __restrict__ s0, fp16* __restrict__ s1,
    fp16* __restrict__ s2, fp16* __restrict__ s3)
{
    __shared__ short sA[BM * 64];
    __shared__ short sB[BN * 64];
    const int tid = threadIdx.x;
    const int col0 = blockIdx.x * BN;
    const int row0 = blockIdx.y * BM;
    const int wave = tid >> 6;
    const int lane = tid & 63;
    constexpr int NJ = (BM == 64) ? 2 : (BN / 32);          // 64x128:2, 128x64:2... see wc
    constexpr int NJR = (BM == 64 || BN == 64) ? 2 : 4;     // frags per wave in N
    const int wr = (BM == 128) ? ((wave >> 1) * 64) : 0;
    const int wc = (BM == 64) ? (wave * 32) : ((wave & 1) * (BN / 2));
    const int lr = lane & 15;
    const int q  = lane >> 4;       // logical 16B chunk within 32-col substep
    const int sw = lane & 7;        // row&7 of every row this lane reads

    const int kpb = K / gridDim.z;
    const int kbeg = blockIdx.z * kpb;
    const int kend = kbeg + kpb;

    const int r0 = tid >> 3;                               // 0..31 (LDS row per pass)
    const int kc  = (tid & 7) << 3;                        // linear LDS dest chunk (shorts)
    const int kcs = (((tid & 7) ^ ((tid >> 3) & 7)) << 3); // swizzled global src chunk

    f32x4 acc[4][NJR] = {};

    for (int k0 = kbeg; k0 < kend; k0 += 64) {
        #pragma unroll
        for (int p = 0; p < BM / 32; p++) {
            int r = r0 + p * 32;
            gld16(A + (size_t)(row0 + r) * lda + k0 + kcs, &sA[r * 64 + kc]);
        }
        #pragma unroll
        for (int p = 0; p < BN / 32; p++) {
            int rr = r0 + p * 32;
            int nb = col0 + rr; if (nb > N - 1) nb = N - 1;   // clamp (epilogue guards)
            gld16(Bw + (size_t)nb * ldb + k0 + kcs, &sB[rr * 64 + kc]);
        }
        __syncthreads();
        bf16x8 af[2][4], bfr[2][NJR];
        #pragma unroll
        for (int kk = 0; kk < 2; kk++) {
            const int cs = ((kk * 4 + q) ^ sw) << 3;
            #pragma unroll
            for (int i = 0; i < 4; i++)
                af[kk][i] = *(const bf16x8*)(&sA[(wr + i * 16 + lr) * 64 + cs]);
            #pragma unroll
            for (int j = 0; j < NJR; j++)
                bfr[kk][j] = *(const bf16x8*)(&sB[(wc + j * 16 + lr) * 64 + cs]);
        }
        #pragma unroll
        for (int kk = 0; kk < 2; kk++)
            #pragma unroll
            for (int i = 0; i < 4; i++)
                #pragma unroll
                for (int j = 0; j < NJR; j++)
                    acc[i][j] = __builtin_amdgcn_mfma_f32_16x16x32_bf16(af[kk][i], bfr[kk][j], acc[i][j], 0, 0, 0);
        __syncthreads();
    }

    fp16* oslice = s0;
    if (MODE == MODE_OUT) {
        int z = blockIdx.z;
        oslice = (z == 0) ? s0 : (z == 1) ? s1 : (z == 2) ? s2 : s3;
    }
    const int drow = (lane >> 4) << 2;
    const int dcol = lane & 15;
    #pragma unroll
    for (int i = 0; i < 4; i++) {
        #pragma unroll
        for (int j = 0; j < NJR; j++) {
            int n = col0 + wc + j * 16 + dcol;
            if (n >= N) continue;
            float bv = bias ? bias[n] : 0.f;
            #pragma unroll
            for (int r = 0; r < 4; r++) {
                int m = row0 + wr + i * 16 + drow + r;
                float v = acc[i][j][r];
                if (MODE == MODE_PROJ) {
                    v += bv;
                    if (n < DI) outh2[(size_t)m * DI + n] = (bf16)v;         // h bf16
                    else        outh[(size_t)m * DI + (n - DI)] = (bf16)v;   // gate bf16
                } else if (MODE == MODE_XPROJ) {
                    s0[(size_t)blockIdx.z * (BLM * 160) + (size_t)m * 160 + n] = (fp16)v;
                } else if (MODE == MODE_DT) {
                    s0[(size_t)m * DI + n] = (fp16)softplusf_(v + bv);       // dt fp16
                } else { // MODE_OUT: fp16 per-slice partial
                    oslice[(size_t)m * HH + n] = (fp16)v;
                }
            }
        }
    }
}

// fused: depthwise causal conv K=4 + silu, 8 d's/thread (vectorized bf16x8 loads),
// AND out_w fp32->bf16 conversion appended.
__global__ __launch_bounds__(256) void conv_cvtow(
    const bf16* __restrict__ h, const float* __restrict__ conv_w,
    const float* __restrict__ conv_b, bf16* __restrict__ hs_b,
    const float* __restrict__ ow, bf16* __restrict__ ow_b)
{
    int i = blockIdx.x * 256 + threadIdx.x;
    int stride = gridDim.x * 256;
    for (; i < CONV8_N + CVT4_N; i += stride) {
        if (i < CONV8_N) {
            int idx = i << 3;                  // element index, multiple of 8
            int d0 = idx & (DI - 1);
            int l = (idx >> 12) & (LL - 1);
            float4 cb0 = *(const float4*)&conv_b[d0];
            float4 cb1 = *(const float4*)&conv_b[d0 + 4];
            float acc[8] = {cb0.x, cb0.y, cb0.z, cb0.w, cb1.x, cb1.y, cb1.z, cb1.w};
            float4 w[8];
            #pragma unroll
            for (int j = 0; j < 8; j++) w[j] = *(const float4*)&conv_w[(d0 + j) * KK];
            #pragma unroll
            for (int k = 0; k < KK; k++) {
                int ls = l - (KK - 1) + k;
                if (ls >= 0) {
                    bf16x8 hv = *(const bf16x8*)&h[(size_t)idx + (size_t)(ls - l) * DI];
                    #pragma unroll
                    for (int j = 0; j < 8; j++)
                        acc[j] += b2f(hv[j]) * ((const float*)&w[j])[k];
                }
            }
            uint4 o;
            float s0 = acc[0] * sigmoidf_(acc[0]), s1 = acc[1] * sigmoidf_(acc[1]);
            float s2 = acc[2] * sigmoidf_(acc[2]), s3 = acc[3] * sigmoidf_(acc[3]);
            float s4 = acc[4] * sigmoidf_(acc[4]), s5 = acc[5] * sigmoidf_(acc[5]);
            float s6 = acc[6] * sigmoidf_(acc[6]), s7 = acc[7] * sigmoidf_(acc[7]);
            o.x = bfpack(s0, s1); o.y = bfpack(s2, s3);
            o.z = bfpack(s4, s5); o.w = bfpack(s6, s7);
            *(uint4*)&hs_b[idx] = o;
        } else {
            cvt_seg(ow, ow_b, i - CONV8_N);
        }
    }
}

// sum 16 fp16 xproj slices -> sp fp32; cols<128 also -> ts bf16 (2 cols/thread,
// 320 blocks for occupancy; coalesced 4B loads)
__global__ __launch_bounds__(256) void reduce_sp(
    const fp16* __restrict__ spS, float* __restrict__ sp_f, bf16* __restrict__ ts_b)
{
    int i = blockIdx.x * 256 + threadIdx.x;     // 81920 items (exact)
    int row = i / 80, c2 = (i % 80) * 2;
    float r0 = 0.f, r1 = 0.f;
    #pragma unroll
    for (int z = 0; z < ZXP; z++) {
        half2v v = *(const half2v*)&spS[(size_t)z * (BLM * 160) + (size_t)row * 160 + c2];
        r0 += (float)v[0]; r1 += (float)v[1];
    }
    *(float2*)&sp_f[(size_t)row * 160 + c2] = make_float2(r0, r1);
    if (c2 < RR) *(unsigned*)&ts_b[(size_t)row * RR + c2] = bfpack(r0, r1);
}

// sum 4 fp16 out slices + bias -> d_out fp32 (8 elems/thread)
__global__ __launch_bounds__(256) void reduce_out(
    const fp16* __restrict__ s0, const fp16* __restrict__ s1,
    const fp16* __restrict__ s2, const fp16* __restrict__ s3,
    const float* __restrict__ bias, float* __restrict__ out)
{
    int i = blockIdx.x * 256 + threadIdx.x;     // 262144 groups of 8
    int c8 = (i & 255) << 3;
    half8 a = ((const half8*)s0)[i];
    half8 b = ((const half8*)s1)[i];
    half8 c = ((const half8*)s2)[i];
    half8 d = ((const half8*)s3)[i];
    float r[8];
    #pragma unroll
    for (int e = 0; e < 8; e++)
        r[e] = (float)a[e] + (float)b[e] + (float)c[e] + (float)d[e] + bias[c8 + e];
    ((float4*)out)[2 * i]     = make_float4(r[0], r[1], r[2], r[3]);
    ((float4*)out)[2 * i + 1] = make_float4(r[4], r[5], r[6], r[7]);
}

// Chunked scan pass 1, 4-way n-split by WAVE: wave ng owns states 4ng..4ng+3,
// lanes = 64 consecutive d -> fully coalesced dt/hs loads and P/S stores.
__global__ __launch_bounds__(256) void scan_part1(
    const fp16* __restrict__ dtr, const float* __restrict__ sp,
    const bf16* __restrict__ hs_b, const float* __restrict__ A_log,
    float* __restrict__ P_ws, float* __restrict__ S_ws)
{
    int bid = blockIdx.x;
    int c  = bid & (CN - 1);
    int db = (bid >> 4) & 63;          // DI/64
    int b  = bid >> 10;
    int ng = threadIdx.x >> 6;         // wave id -> state group
    int d  = db * 64 + (threadIdx.x & 63);
    int n0 = ng * 4;

    float A[4], P[4], S[4];
    #pragma unroll
    for (int k = 0; k < 4; k++) {
        A[k] = -__expf(A_log[d * NST + n0 + k]);
        P[k] = 1.f; S[k] = 0.f;
    }
    const float* spb = sp + (size_t)b * LL * 160;
    size_t base = (size_t)b * LL * DI + d;
    for (int l = c * LC; l < (c + 1) * LC; l++) {
        size_t off = base + (size_t)l * DI;
        float dtv = (float)dtr[off];
        float hsv = (float)hs_b[off];
        float dh = dtv * hsv;
        #pragma unroll
        for (int k = 0; k < 4; k++) {
            float a  = __expf(dtv * A[k]);
            float Bn = spb[l * 160 + RR + n0 + k];
            S[k] = a * S[k] + dh * Bn;
            P[k] *= a;
        }
    }
    size_t ob = (size_t)(b * CN + c) * NST * DI + (size_t)n0 * DI + d;
    #pragma unroll
    for (int k = 0; k < 4; k++) {
        P_ws[ob + (size_t)k * DI] = P[k];
        S_ws[ob + (size_t)k * DI] = S[k];
    }
}

// Hierarchical prefix: scan the CN chunk summaries per (b,n,d); overwrite S_ws
// with each chunk's INITIAL state (I[c] = state before chunk c). ~24MB traffic.
__global__ __launch_bounds__(256) void scan_mid(
    const float* __restrict__ P_ws, float* __restrict__ S_ws)
{
    int bid = blockIdx.x;
    int n  = bid & (NST - 1);
    int db = (bid >> 4) & (DI / 256 - 1);
    int b  = bid >> 8;
    int d  = db * 256 + threadIdx.x;
    size_t base = (size_t)n * DI + d;
    float s = 0.f;
    for (int c = 0; c < CN; c++) {
        size_t idx = (size_t)(b * CN + c) * NST * DI + base;
        float p  = P_ws[idx];
        float sv = S_ws[idx];
        S_ws[idx] = s;            // init state for chunk c
        s = p * s + sv;
    }
}

// Pass 2, 4-way n-split within wave (shfl y-reduce): load chunk-init state from
// I (=S_ws), local scan, y closed with two width-4 shfl_xor adds.
__global__ __launch_bounds__(256) void scan_part2(
    const fp16* __restrict__ dtr, const float* __restrict__ sp,
    const bf16* __restrict__ hs_b, const bf16* __restrict__ g_b,
    const float* __restrict__ A_log, const float* __restrict__ Dv,
    const float* __restrict__ I_ws, bf16* __restrict__ y_b)
{
    int bid = blockIdx.x;
    int c  = bid & (CN - 1);
    int db = (bid >> 4) & 63;          // DI/64
    int b  = bid >> 10;
    int ng = threadIdx.x & 3;
    int d  = db * 64 + (threadIdx.x >> 2);
    int n0 = ng * 4;

    float A[4], s[4];
    #pragma unroll
    for (int k = 0; k < 4; k++)
        A[k] = -__expf(A_log[d * NST + n0 + k]);
    size_t ib = (size_t)(b * CN + c) * NST * DI + (size_t)n0 * DI + d;
    #pragma unroll
    for (int k = 0; k < 4; k++) s[k] = I_ws[ib + (size_t)k * DI];
    float Dd = Dv[d];

    const float* spb = sp + (size_t)b * LL * 160;
    size_t base = (size_t)b * LL * DI + d;
    for (int l = c * LC; l < (c + 1) * LC; l++) {
        size_t off = base + (size_t)l * DI;
        float dtv = (float)dtr[off];
        float hsv = (float)hs_b[off];
        float dh = dtv * hsv;
        float y = 0.f;
        #pragma unroll
        for (int k = 0; k < 4; k++) {
            float a  = __expf(dtv * A[k]);
            float Bn = spb[l * 160 + RR + n0 + k];
            float Cn = spb[l * 160 + RR + NST + n0 + k];
            s[k] = a * s[k] + dh * Bn;
            y += s[k] * Cn;
        }
        y += __shfl_xor(y, 1);
        y += __shfl_xor(y, 2);
        if (ng == 0) {
            float gv = (float)g_b[off];
            y_b[off] = (bf16)((y + hsv * Dd) * (gv * sigmoidf_(gv)));
        }
    }
}

extern "C" void kernel_launch(void* const* d_in, const int* in_sizes, int n_in,
                              void* d_out, int out_size, void* d_ws, size_t ws_size,
                              hipStream_t stream)
{
    const float* x       = (const float*)d_in[0];
    const float* in_w    = (const float*)d_in[1];
    const float* in_b    = (const float*)d_in[2];
    const float* conv_w  = (const float*)d_in[3];
    const float* conv_b  = (const float*)d_in[4];
    const float* xproj_w = (const float*)d_in[5];
    const float* dt_w    = (const float*)d_in[6];
    const float* dt_b    = (const float*)d_in[7];
    const float* A_log   = (const float*)d_in[8];
    const float* Dv      = (const float*)d_in[9];
    const float* out_w   = (const float*)d_in[10];
    const float* out_b   = (const float*)d_in[11];
    float* out = (float*)d_out;

    // Overlay layout, 67.2 MB peak.
    // [0,8):   h_b (D1-D2) -> spS fp16 5.25 (D3-D4) -> P (D6, dead after mid) -> oS0[0,4)+oS1[4,8) (D8-D9)
    // [8,16):  x_b [8,12) (D0-D1) -> S/I (D6-D7) -> oS2[8,12)+oS3[12,16) (D8-D9)
    // [16,32): in_w_b part (D0-D1) -> ow_b bf16 (D2-D8)
    // [32,40): in_w_b part -> y_b (D7-D8)
    // [40,48): in_w_b part -> dt_h fp16 (D5-D7)
    // [48,56): hs_b (D2-D7)
    // [56,64): g_b (D1-D7)
    // [64,67.2): sp_f, ts_b, xw_b, dtw_b
    char* ws = (char*)d_ws;
    const size_t MB = 1u << 20;
    bf16*  h_b    = (bf16*)(ws);
    fp16*  spS    = (fp16*)(ws);
    float* P_ws   = (float*)(ws);
    fp16*  oS0    = (fp16*)(ws);
    fp16*  oS1    = (fp16*)(ws + 4 * MB);
    bf16*  x_b    = (bf16*)(ws + 8 * MB);
    float* S_ws   = (float*)(ws + 8 * MB);
    fp16*  oS2    = (fp16*)(ws + 8 * MB);
    fp16*  oS3    = (fp16*)(ws + 12 * MB);
    bf16*  in_w_b = (bf16*)(ws + 16 * MB);
    bf16*  ow_b   = (bf16*)(ws + 16 * MB);
    bf16*  y_b    = (bf16*)(ws + 32 * MB);
    fp16*  dt_h   = (fp16*)(ws + 40 * MB);
    bf16*  hs_b   = (bf16*)(ws + 48 * MB);
    bf16*  g_b    = (bf16*)(ws + 56 * MB);
    char* p = ws + 64 * MB;
    float* sp_f = (float*)p; p += (size_t)BLM * 160 * 4;        // 0.625 MB
    bf16*  ts_b = (bf16*)p;  p += (size_t)BLM * RR * 2;         // 0.25 MB
    bf16*  xw_b = (bf16*)p;  p += (size_t)(RR + 2 * NST) * DI * 2;  // 1.25 MB
    bf16*  dtw_b= (bf16*)p;  p += (size_t)DI * RR * 2;          // 1 MB

    // D0: fused convert x + in_w + xproj_w + dt_w to bf16
    cvt_all<<<2048, 256, 0, stream>>>(
        x, x_b, BLM * HH / 4,
        in_w, in_w_b, 2 * DI * HH / 4,
        xproj_w, xw_b, (RR + 2 * NST) * DI / 4,
        dt_w, dtw_b, DI * RR / 4);
    // D1: proj = x @ in_w^T + in_b -> h bf16, gate bf16 (128x128 tile)
    gemm_bf16<128, 128, MODE_PROJ><<<dim3((2 * DI) / 128, BLM / 128, 1), 256, 0, stream>>>(
        x_b, in_w_b, 2 * DI, HH, HH, HH, in_b, g_b, h_b,
        nullptr, nullptr, nullptr, nullptr);
    // D2: conv+silu -> hs bf16 (8 d/thread); fused out_w fp32->bf16
    conv_cvtow<<<2048, 256, 0, stream>>>(h_b, conv_w, conv_b, hs_b, out_w, ow_b);
    // D3: sp partials fp16 (BM=64, split-K=16)
    gemm_bf16<64, 128, MODE_XPROJ><<<dim3(2, BLM / 64, ZXP), 256, 0, stream>>>(
        hs_b, xw_b, RR + 2 * NST, DI, DI, DI, nullptr, nullptr, nullptr,
        spS, nullptr, nullptr, nullptr);
    // D4: reduce fp16 slices -> sp fp32 + ts bf16 (320 blocks)
    reduce_sp<<<320, 256, 0, stream>>>(spS, sp_f, ts_b);
    // D5: dt = softplus(ts @ dt_w^T + dt_b) -> fp16
    gemm_bf16<64, 128, MODE_DT><<<dim3(DI / 128, BLM / 64, 1), 256, 0, stream>>>(
        ts_b, dtw_b, DI, RR, RR, RR, dt_b, nullptr, nullptr,
        dt_h, nullptr, nullptr, nullptr);
    // D6: chunk summaries (wave-n-split, coalesced)
    scan_part1<<<BB * (DI / 64) * CN, 256, 0, stream>>>(
        dt_h, sp_f, hs_b, A_log, P_ws, S_ws);
    // D6.5: hierarchical prefix -> chunk-initial states in-place over S_ws
    scan_mid<<<BB * NST * (DI / 256), 256, 0, stream>>>(P_ws, S_ws);
    // D7: local rescan + y emit (no prefix loop)
    scan_part2<<<BB * (DI / 64) * CN, 256, 0, stream>>>(
        dt_h, sp_f, hs_b, g_b, A_log, Dv, S_ws, y_b);
    // D8: out partials (128x128 tile, split-K=4; fp16 per-slice stores)
    gemm_bf16<128, 128, MODE_OUT><<<dim3(HH / 128, BLM / 128, ZOUT), 256, 0, stream>>>(
        y_b, ow_b, HH, DI, DI, DI, nullptr, nullptr, nullptr,
        oS0, oS1, oS2, oS3);
    // D9: reduce fp16 + bias -> d_out
    reduce_out<<<1024, 256, 0, stream>>>(oS0, oS1, oS2, oS3, out_b, out);
}